// Round 1
// baseline (1151.339 us; speedup 1.0000x reference)
//
#include <hip/hip_runtime.h>

// Fused 4-layer RNN (LSTM,LSTM,GRU,GRU, H=64) + FC head.
// B=2048, T=512. Grid=256 blocks x 256 threads (4 waves), 8 batch rows/block.
// All recurrent weights live in VGPRs as MFMA B-fragments (bf16); states fp32
// in registers; per-step z vectors staged bf16 in LDS.

#define TT 512
#define HH 64

typedef __attribute__((ext_vector_type(8))) short bfrag;  // 8 bf16
typedef __attribute__((ext_vector_type(4))) float facc;   // 4 f32

#define MFMA(a,b,c) __builtin_amdgcn_mfma_f32_16x16x32_bf16((a),(b),(c),0,0,0)

__device__ __forceinline__ short f2bf(float f){
  union { float f; unsigned u; } v; v.f = f;
  unsigned r = (v.u + 0x7fffu + ((v.u >> 16) & 1u)) >> 16;  // RNE
  return (short)r;
}
__device__ __forceinline__ float sigm(float xx){
  return __builtin_amdgcn_rcpf(1.0f + __expf(-xx));
}
__device__ __forceinline__ float tanh_(float xx){
  return 2.0f * __builtin_amdgcn_rcpf(1.0f + __expf(-2.0f * xx)) - 1.0f;
}

// LDS row strides (bf16 elems). Odd multiples of 8 -> 16B-aligned rows,
// row stride = odd*16B so b128 reads spread banks (~2-way, free).
#define RB0 72    // K=64 buffer (LSTM0)
#define RB1 136   // K=128 buffers

__global__ __launch_bounds__(256, 1) void rnn_fused(
    const float* __restrict__ x,
    const float* __restrict__ lw_ih0, const float* __restrict__ lw_hh0,
    const float* __restrict__ lb_ih0, const float* __restrict__ lb_hh0,
    const float* __restrict__ lw_ih1, const float* __restrict__ lw_hh1,
    const float* __restrict__ lb_ih1, const float* __restrict__ lb_hh1,
    const float* __restrict__ gw_ih0, const float* __restrict__ gw_hh0,
    const float* __restrict__ gb_ih0, const float* __restrict__ gb_hh0,
    const float* __restrict__ gw_ih1, const float* __restrict__ gw_hh1,
    const float* __restrict__ gb_ih1, const float* __restrict__ gb_hh1,
    const float* __restrict__ fc_w, const float* __restrict__ fc_b,
    float* __restrict__ out)
{
  __shared__ __align__(16) short zL0[16 * RB0];  // h0 state (K=64)
  __shared__ __align__(16) short zL1[16 * RB1];  // [h0_t | h1_prev]
  __shared__ __align__(16) short zG0[16 * RB1];  // [h1_t | hg0_prev]
  __shared__ __align__(16) short zG1[16 * RB1];  // [hg0_t | hg1_prev]
  __shared__ float xs[8][128];
  __shared__ float hfin[16][HH];

  const int tid = threadIdx.x;
  const int w   = tid >> 6;      // wave 0..3
  const int l   = tid & 63;
  const int lq  = l >> 4;        // quarter-group
  const int lc  = l & 15;        // col within tile
  const int r0  = lq * 4;        // C-layout row base
  const int dl  = w * 16 + lc;   // this lane's h-dim (0..63)
  const int kb  = lq * 8;        // frag k-offset within 32-K tile
  const int rb0 = blockIdx.x * 8;

  // ---------------- load weight fragments (once) ----------------
  // B-frag layout (16x16x32): col = lane&15, k = (lane>>4)*8 + j.
  bfrag wL0f[4][2];  // LSTM0 w_hh: gates i,f,g,o x K-tiles{0,1}
  bfrag wL1f[4][4];  // LSTM1 [w_ih1 | w_hh1]: K-tiles 0,1=ih 2,3=hh
  bfrag wg0x[3][2], wg0h[3][2], wg1x[3][2], wg1h[3][2]; // GRU r,z,n

  #pragma unroll
  for (int G = 0; G < 4; ++G) {
    const int jw = G * 64 + dl;
    #pragma unroll
    for (int kt = 0; kt < 2; ++kt) {
      bfrag f;
      #pragma unroll
      for (int j = 0; j < 8; ++j) f[j] = f2bf(lw_hh0[jw * 64 + kt * 32 + kb + j]);
      wL0f[G][kt] = f;
    }
    #pragma unroll
    for (int kt = 0; kt < 4; ++kt) {
      const float* Wsrc = (kt < 2) ? lw_ih1 : lw_hh1;
      const int kofs = (kt < 2) ? kt * 32 : (kt - 2) * 32;
      bfrag f;
      #pragma unroll
      for (int j = 0; j < 8; ++j) f[j] = f2bf(Wsrc[jw * 64 + kofs + kb + j]);
      wL1f[G][kt] = f;
    }
  }
  #pragma unroll
  for (int G = 0; G < 3; ++G) {
    const int jw = G * 64 + dl;
    #pragma unroll
    for (int kt = 0; kt < 2; ++kt) {
      bfrag f0, f1, f2, f3;
      #pragma unroll
      for (int j = 0; j < 8; ++j) {
        const int o = jw * 64 + kt * 32 + kb + j;
        f0[j] = f2bf(gw_ih0[o]);
        f1[j] = f2bf(gw_hh0[o]);
        f2[j] = f2bf(gw_ih1[o]);
        f3[j] = f2bf(gw_hh1[o]);
      }
      wg0x[G][kt] = f0; wg0h[G][kt] = f1; wg1x[G][kt] = f2; wg1h[G][kt] = f3;
    }
  }

  // per-lane biases / LSTM0 input weights
  float bL0[4], bL1[4], wx0[4];
  #pragma unroll
  for (int G = 0; G < 4; ++G) {
    bL0[G] = lb_ih0[G * 64 + dl] + lb_hh0[G * 64 + dl];
    bL1[G] = lb_ih1[G * 64 + dl] + lb_hh1[G * 64 + dl];
    wx0[G] = lw_ih0[G * 64 + dl];   // [4H,1]
  }
  float bx0[3], bh0[3], bx1[3], bh1[3];
  #pragma unroll
  for (int G = 0; G < 3; ++G) {
    bx0[G] = gb_ih0[G * 64 + dl];
    bh0[G] = gb_hh0[G * 64 + dl];
    bx1[G] = gb_ih1[G * 64 + dl];
    bh1[G] = gb_hh1[G * 64 + dl];
  }

  // zero LDS state buffers (h=0, c=0 at t=0)
  for (int i = tid; i < 16 * RB0; i += 256) zL0[i] = 0;
  for (int i = tid; i < 16 * RB1; i += 256) { zL1[i] = 0; zG0[i] = 0; zG1[i] = 0; }
  __syncthreads();

  facc c0 = {0.f, 0.f, 0.f, 0.f}, c1 = {0.f, 0.f, 0.f, 0.f};
  facc hg0 = {0.f, 0.f, 0.f, 0.f}, hg1 = {0.f, 0.f, 0.f, 0.f};

  #pragma unroll 1
  for (int t = 0; t < TT; ++t) {
    if ((t & 127) == 0) {  // stage 128 timesteps of x for our 8 rows
      const int row = tid >> 5, tq = (tid & 31) * 4;
      const float4 v = *(const float4*)(x + (rb0 + row) * TT + t + tq);
      *(float4*)&xs[row][tq] = v;
      __syncthreads();
    }

    // ---------------- LSTM layer 0 ----------------
    {
      const bfrag a0 = *(const bfrag*)(zL0 + lc * RB0 + 0 * 32 + kb);
      const bfrag a1 = *(const bfrag*)(zL0 + lc * RB0 + 1 * 32 + kb);
      facc acc[4];
      #pragma unroll
      for (int G = 0; G < 4; ++G) {
        facc a_ = {0.f, 0.f, 0.f, 0.f};
        a_ = MFMA(a0, wL0f[G][0], a_);
        a_ = MFMA(a1, wL0f[G][1], a_);
        acc[G] = a_;
      }
      float xv[4];
      #pragma unroll
      for (int m = 0; m < 4; ++m) xv[m] = xs[(r0 + m) & 7][t & 127];
      short hb[4];
      #pragma unroll
      for (int m = 0; m < 4; ++m) {
        const float i_ = sigm (acc[0][m] + xv[m] * wx0[0] + bL0[0]);
        const float f_ = sigm (acc[1][m] + xv[m] * wx0[1] + bL0[1]);
        const float g_ = tanh_(acc[2][m] + xv[m] * wx0[2] + bL0[2]);
        const float o_ = sigm (acc[3][m] + xv[m] * wx0[3] + bL0[3]);
        c0[m] = f_ * c0[m] + i_ * g_;
        hb[m] = f2bf(o_ * tanh_(c0[m]));
      }
      __syncthreads();  // all waves done reading zL0
      #pragma unroll
      for (int m = 0; m < 4; ++m) {
        zL0[(r0 + m) * RB0 + dl] = hb[m];        // h0 for next step
        zL1[(r0 + m) * RB1 + dl] = hb[m];        // input to LSTM1
      }
      __syncthreads();
    }

    // ---------------- LSTM layer 1 ----------------
    {
      const bfrag a0 = *(const bfrag*)(zL1 + lc * RB1 + 0 * 32 + kb);
      const bfrag a1 = *(const bfrag*)(zL1 + lc * RB1 + 1 * 32 + kb);
      const bfrag a2 = *(const bfrag*)(zL1 + lc * RB1 + 2 * 32 + kb);
      const bfrag a3 = *(const bfrag*)(zL1 + lc * RB1 + 3 * 32 + kb);
      facc acc[4];
      #pragma unroll
      for (int G = 0; G < 4; ++G) {
        facc a_ = {0.f, 0.f, 0.f, 0.f};
        a_ = MFMA(a0, wL1f[G][0], a_);
        a_ = MFMA(a1, wL1f[G][1], a_);
        a_ = MFMA(a2, wL1f[G][2], a_);
        a_ = MFMA(a3, wL1f[G][3], a_);
        acc[G] = a_;
      }
      short hb[4];
      #pragma unroll
      for (int m = 0; m < 4; ++m) {
        const float i_ = sigm (acc[0][m] + bL1[0]);
        const float f_ = sigm (acc[1][m] + bL1[1]);
        const float g_ = tanh_(acc[2][m] + bL1[2]);
        const float o_ = sigm (acc[3][m] + bL1[3]);
        c1[m] = f_ * c1[m] + i_ * g_;
        hb[m] = f2bf(o_ * tanh_(c1[m]));
      }
      __syncthreads();
      #pragma unroll
      for (int m = 0; m < 4; ++m) {
        zL1[(r0 + m) * RB1 + 64 + dl] = hb[m];   // h1 for next step
        zG0[(r0 + m) * RB1 + dl]      = hb[m];   // input to GRU0
      }
      __syncthreads();
    }

    // ---------------- GRU layer 0 ----------------
    {
      const bfrag a0 = *(const bfrag*)(zG0 + lc * RB1 + 0 * 32 + kb);
      const bfrag a1 = *(const bfrag*)(zG0 + lc * RB1 + 1 * 32 + kb);
      const bfrag a2 = *(const bfrag*)(zG0 + lc * RB1 + 2 * 32 + kb);
      const bfrag a3 = *(const bfrag*)(zG0 + lc * RB1 + 3 * 32 + kb);
      facc gx[3], gh[3];
      #pragma unroll
      for (int G = 0; G < 3; ++G) {
        facc a_ = {0.f, 0.f, 0.f, 0.f};
        a_ = MFMA(a0, wg0x[G][0], a_);
        a_ = MFMA(a1, wg0x[G][1], a_);
        gx[G] = a_;
        facc b_ = {0.f, 0.f, 0.f, 0.f};
        b_ = MFMA(a2, wg0h[G][0], b_);
        b_ = MFMA(a3, wg0h[G][1], b_);
        gh[G] = b_;
      }
      short hb[4];
      #pragma unroll
      for (int m = 0; m < 4; ++m) {
        const float r_ = sigm (gx[0][m] + bx0[0] + gh[0][m] + bh0[0]);
        const float z_ = sigm (gx[1][m] + bx0[1] + gh[1][m] + bh0[1]);
        const float n_ = tanh_(gx[2][m] + bx0[2] + r_ * (gh[2][m] + bh0[2]));
        hg0[m] = (1.0f - z_) * n_ + z_ * hg0[m];
        hb[m] = f2bf(hg0[m]);
      }
      __syncthreads();
      #pragma unroll
      for (int m = 0; m < 4; ++m) {
        zG0[(r0 + m) * RB1 + 64 + dl] = hb[m];   // hg0 for next step
        zG1[(r0 + m) * RB1 + dl]      = hb[m];   // input to GRU1
      }
      __syncthreads();
    }

    // ---------------- GRU layer 1 ----------------
    {
      const bfrag a0 = *(const bfrag*)(zG1 + lc * RB1 + 0 * 32 + kb);
      const bfrag a1 = *(const bfrag*)(zG1 + lc * RB1 + 1 * 32 + kb);
      const bfrag a2 = *(const bfrag*)(zG1 + lc * RB1 + 2 * 32 + kb);
      const bfrag a3 = *(const bfrag*)(zG1 + lc * RB1 + 3 * 32 + kb);
      facc gx[3], gh[3];
      #pragma unroll
      for (int G = 0; G < 3; ++G) {
        facc a_ = {0.f, 0.f, 0.f, 0.f};
        a_ = MFMA(a0, wg1x[G][0], a_);
        a_ = MFMA(a1, wg1x[G][1], a_);
        gx[G] = a_;
        facc b_ = {0.f, 0.f, 0.f, 0.f};
        b_ = MFMA(a2, wg1h[G][0], b_);
        b_ = MFMA(a3, wg1h[G][1], b_);
        gh[G] = b_;
      }
      short hb[4];
      #pragma unroll
      for (int m = 0; m < 4; ++m) {
        const float r_ = sigm (gx[0][m] + bx1[0] + gh[0][m] + bh1[0]);
        const float z_ = sigm (gx[1][m] + bx1[1] + gh[1][m] + bh1[1]);
        const float n_ = tanh_(gx[2][m] + bx1[2] + r_ * (gh[2][m] + bh1[2]));
        hg1[m] = (1.0f - z_) * n_ + z_ * hg1[m];
        hb[m] = f2bf(hg1[m]);
      }
      __syncthreads();
      #pragma unroll
      for (int m = 0; m < 4; ++m) zG1[(r0 + m) * RB1 + 64 + dl] = hb[m];
      __syncthreads();
    }
  }

  // ---------------- FC head: out[b] = hg1_T[b,:] . fc_w + fc_b ----------------
  #pragma unroll
  for (int m = 0; m < 4; ++m) hfin[r0 + m][dl] = hg1[m];
  __syncthreads();
  if (tid < 8) {
    float s = fc_b[0];
    for (int d = 0; d < HH; ++d) s += hfin[tid][d] * fc_w[d];
    out[rb0 + tid] = s;
  }
}

extern "C" void kernel_launch(void* const* d_in, const int* in_sizes, int n_in,
                              void* d_out, int out_size, void* d_ws, size_t ws_size,
                              hipStream_t stream) {
  const float* x      = (const float*)d_in[0];
  const float* lw_ih0 = (const float*)d_in[1];
  const float* lw_hh0 = (const float*)d_in[2];
  const float* lb_ih0 = (const float*)d_in[3];
  const float* lb_hh0 = (const float*)d_in[4];
  const float* lw_ih1 = (const float*)d_in[5];
  const float* lw_hh1 = (const float*)d_in[6];
  const float* lb_ih1 = (const float*)d_in[7];
  const float* lb_hh1 = (const float*)d_in[8];
  const float* gw_ih0 = (const float*)d_in[9];
  const float* gw_hh0 = (const float*)d_in[10];
  const float* gb_ih0 = (const float*)d_in[11];
  const float* gb_hh0 = (const float*)d_in[12];
  const float* gw_ih1 = (const float*)d_in[13];
  const float* gw_hh1 = (const float*)d_in[14];
  const float* gb_ih1 = (const float*)d_in[15];
  const float* gb_hh1 = (const float*)d_in[16];
  const float* fc_w   = (const float*)d_in[17];
  const float* fc_b   = (const float*)d_in[18];

  rnn_fused<<<dim3(2048 / 8), dim3(256), 0, stream>>>(
      x, lw_ih0, lw_hh0, lb_ih0, lb_hh0, lw_ih1, lw_hh1, lb_ih1, lb_hh1,
      gw_ih0, gw_hh0, gb_ih0, gb_hh0, gw_ih1, gw_hh1, gb_ih1, gb_hh1,
      fc_w, fc_b, (float*)d_out);
}